// Round 1
// baseline (1806.488 us; speedup 1.0000x reference)
//
#include <hip/hip_runtime.h>

#define D 32
#define HASH_BITS 20
#define HASH_SIZE (1u << HASH_BITS)
#define EMPTY_KEY 0xFFFFFFFFu

// ---------------------------------------------------------------------------
// Kernel 1: dedup edges via concurrent hash set; winner scatters x rows into
// msg (= d_out) with f32 atomics. Symmetric: msg[s]+=x[d], msg[d]+=x[s];
// self-loop contributes exactly once.
// ---------------------------------------------------------------------------
__global__ void gnn_edge_scatter(const int* __restrict__ src,
                                 const int* __restrict__ dst,
                                 const float* __restrict__ x,
                                 float* __restrict__ msg,
                                 unsigned int* __restrict__ htab,
                                 int E) {
    int e = blockIdx.x * blockDim.x + threadIdx.x;
    if (e >= E) return;
    int s = src[e];
    int d = dst[e];
    int a = s < d ? s : d;
    int b = s < d ? d : s;
    unsigned int key = ((unsigned int)a << 14) | (unsigned int)b;  // N=16384 -> 28 bits
    unsigned int h = (key * 2654435761u) >> (32 - HASH_BITS);
    bool inserted;
    for (;;) {
        unsigned int prev = atomicCAS(&htab[h], EMPTY_KEY, key);
        if (prev == EMPTY_KEY) { inserted = true; break; }
        if (prev == key)       { inserted = false; break; }
        h = (h + 1) & (HASH_SIZE - 1);
    }
    if (!inserted) return;  // duplicate edge: adjacency already 1

    const float4* xs = (const float4*)(x + (size_t)s * D);
    const float4* xd = (const float4*)(x + (size_t)d * D);
    if (s == d) {
        float* m = msg + (size_t)s * D;
#pragma unroll
        for (int i = 0; i < D / 4; ++i) {
            float4 v = xs[i];
            atomicAdd(&m[i * 4 + 0], v.x);
            atomicAdd(&m[i * 4 + 1], v.y);
            atomicAdd(&m[i * 4 + 2], v.z);
            atomicAdd(&m[i * 4 + 3], v.w);
        }
    } else {
        float* ms = msg + (size_t)s * D;
        float* md = msg + (size_t)d * D;
#pragma unroll
        for (int i = 0; i < D / 4; ++i) {
            float4 vd = xd[i];
            atomicAdd(&ms[i * 4 + 0], vd.x);
            atomicAdd(&ms[i * 4 + 1], vd.y);
            atomicAdd(&ms[i * 4 + 2], vd.z);
            atomicAdd(&ms[i * 4 + 3], vd.w);
            float4 vs = xs[i];
            atomicAdd(&md[i * 4 + 0], vs.x);
            atomicAdd(&md[i * 4 + 1], vs.y);
            atomicAdd(&md[i * 4 + 2], vs.z);
            atomicAdd(&md[i * 4 + 3], vs.w);
        }
    }
}

// ---------------------------------------------------------------------------
// Kernel 2: fused update. Block = 256 threads = 8 nodes x 32 output dims.
// Reads msg from out (in place), writes updated back. Weights staged in LDS
// with +1 padding (stride 33) so lanes o=0..31 reading W[o][k] hit distinct
// banks ((o*33+k) % 32 = (o+k) % 32).
// ---------------------------------------------------------------------------
__global__ __launch_bounds__(256) void gnn_update(
        const float* __restrict__ x,
        float* __restrict__ out,          // in: messages, out: updated
        const float* __restrict__ W_agg,
        const float* __restrict__ b_agg,
        const float* __restrict__ W_upd,
        const float* __restrict__ b_upd) {
    __shared__ float sWa[D][D + 1];
    __shared__ float sWu[D][D + 1];
    __shared__ float sb[D];               // b_agg + b_upd
    __shared__ float sx[8][D];
    __shared__ float sm[8][D];

    int t = threadIdx.x;
    for (int i = t; i < D * D; i += 256) {
        sWa[i >> 5][i & 31] = W_agg[i];
        sWu[i >> 5][i & 31] = W_upd[i];
    }
    if (t < D) sb[t] = b_agg[t] + b_upd[t];

    int g = t >> 5;                       // node slot within block
    int o = t & 31;                       // output dim
    size_t node = (size_t)blockIdx.x * 8 + g;
    sx[g][o] = x[node * D + o];
    sm[g][o] = out[node * D + o];
    __syncthreads();

    float acc = sb[o];
    const float* wa = sWa[o];
    const float* wu = sWu[o];
    const float* xr = sx[g];
    const float* mr = sm[g];
#pragma unroll
    for (int k = 0; k < D; ++k) {
        acc += xr[k] * wu[k];
        acc += mr[k] * wa[k];
    }
    out[node * D + o] = acc;
}

extern "C" void kernel_launch(void* const* d_in, const int* in_sizes, int n_in,
                              void* d_out, int out_size, void* d_ws, size_t ws_size,
                              hipStream_t stream) {
    const float* x      = (const float*)d_in[0];
    const int*   eidx   = (const int*)d_in[1];
    const float* W_agg  = (const float*)d_in[2];
    const float* b_agg  = (const float*)d_in[3];
    const float* W_upd  = (const float*)d_in[4];
    const float* b_upd  = (const float*)d_in[5];
    float* out = (float*)d_out;

    const int E = in_sizes[1] / 2;
    const int N = in_sizes[0] / D;
    const int* src = eidx;
    const int* dst = eidx + E;

    unsigned int* htab = (unsigned int*)d_ws;

    // zero messages (accumulated in d_out), empty-fill hash table
    hipMemsetAsync(d_out, 0, (size_t)N * D * sizeof(float), stream);
    hipMemsetAsync(htab, 0xFF, (size_t)HASH_SIZE * sizeof(unsigned int), stream);

    gnn_edge_scatter<<<(E + 255) / 256, 256, 0, stream>>>(src, dst, x, out, htab, E);
    gnn_update<<<N / 8, 256, 0, stream>>>(x, out, W_agg, b_agg, W_upd, b_upd);
}

// Round 2
// 171.315 us; speedup vs baseline: 10.5448x; 10.5448x over previous
//
#include <hip/hip_runtime.h>

#define D 32

// ===========================================================================
// FAST PATH (ws_size >= 32 MiB): adjacency bitmap + atomic-free gather.
// ===========================================================================

// Kernel A: set adjacency bits. atomicOr is idempotent -> duplicate edges and
// (a,b)/(b,a) pairs dedupe for free. Self-loop sets one bit -> counted once.
__global__ void gnn_edge_bits(const int* __restrict__ src,
                              const int* __restrict__ dst,
                              unsigned int* __restrict__ bm,
                              int E, int wpr /* words per row = N/32 */) {
    int e = blockIdx.x * blockDim.x + threadIdx.x;
    if (e >= E) return;
    int s = src[e];
    int d = dst[e];
    atomicOr(&bm[(size_t)d * wpr + (s >> 5)], 1u << (s & 31));
    atomicOr(&bm[(size_t)s * wpr + (d >> 5)], 1u << (d & 31));
}

// Kernel B: one wave per node. Scan the node's bitmap row (512 dwords,
// coalesced), sum neighbor x-rows into registers (x is L2-resident), then
// fused epilogue: out = b_upd + b_agg + x*W_upd^T + msg*W_agg^T.
__global__ __launch_bounds__(256) void gnn_gather_update(
        const unsigned int* __restrict__ bm,
        const float* __restrict__ x,
        float* __restrict__ out,
        const float* __restrict__ W_agg,
        const float* __restrict__ b_agg,
        const float* __restrict__ W_upd,
        const float* __restrict__ b_upd,
        int wpr) {
    __shared__ float sWa[D][D + 1];
    __shared__ float sWu[D][D + 1];
    __shared__ float sb[D];
    __shared__ float sx[4][D];
    __shared__ float sm[4][D];

    int t = threadIdx.x;
    for (int i = t; i < D * D; i += 256) {
        sWa[i >> 5][i & 31] = W_agg[i];
        sWu[i >> 5][i & 31] = W_upd[i];
    }
    if (t < D) sb[t] = b_agg[t] + b_upd[t];

    int lane = t & 63;
    int slot = t >> 6;                        // wave slot = node slot (4/block)
    int dim  = lane & 31;
    size_t node = (size_t)blockIdx.x * 4 + slot;

    // stage this node's x row (also used by epilogue)
    float xval = x[node * D + dim];
    if (lane < 32) sx[slot][dim] = xval;

    // ---- bitmap row scan: load all 8 chunks up front (pipelined loads) ----
    const unsigned int* row = bm + node * (size_t)wpr;
    unsigned int w[8];
#pragma unroll
    for (int c = 0; c < 8; ++c) w[c] = row[c * 64 + lane];

    float acc = 0.f;                          // msg[node][dim] (both halves dup)
#pragma unroll
    for (int c = 0; c < 8; ++c) {
        unsigned long long m = __ballot(w[c] != 0);
        while (m) {
            int l = __ffsll((unsigned long long)m) - 1;
            m &= m - 1;
            unsigned int ww = __shfl(w[c], l);
            int basecol = (c << 11) + (l << 5);   // (c*64 + l) * 32
            while (ww) {
                int b = __ffs(ww) - 1;
                ww &= ww - 1;
                acc += x[(size_t)(basecol + b) * D + dim];
            }
        }
    }
    if (lane < 32) sm[slot][dim] = acc;
    __syncthreads();

    // ---- fused epilogue: 4 nodes x 32 outputs on threads 0..127 ----
    if (t < 128) {
        int ns = t >> 5;                      // node slot
        int o  = t & 31;                      // output dim
        float r = sb[o];
        const float* wa = sWa[o];
        const float* wu = sWu[o];
        const float* xr = sx[ns];
        const float* mr = sm[ns];
#pragma unroll
        for (int k = 0; k < D; ++k) {
            r += xr[k] * wu[k];
            r += mr[k] * wa[k];
        }
        out[((size_t)blockIdx.x * 4 + ns) * D + o] = r;
    }
}

// ===========================================================================
// FALLBACK PATH (small ws): round-1 hash-dedup + scattered atomics.
// ===========================================================================
#define HASH_BITS 20
#define HASH_SIZE (1u << HASH_BITS)
#define EMPTY_KEY 0xFFFFFFFFu

__global__ void gnn_edge_scatter(const int* __restrict__ src,
                                 const int* __restrict__ dst,
                                 const float* __restrict__ x,
                                 float* __restrict__ msg,
                                 unsigned int* __restrict__ htab,
                                 int E) {
    int e = blockIdx.x * blockDim.x + threadIdx.x;
    if (e >= E) return;
    int s = src[e];
    int d = dst[e];
    int a = s < d ? s : d;
    int b = s < d ? d : s;
    unsigned int key = ((unsigned int)a << 14) | (unsigned int)b;
    unsigned int h = (key * 2654435761u) >> (32 - HASH_BITS);
    bool inserted;
    for (;;) {
        unsigned int prev = atomicCAS(&htab[h], EMPTY_KEY, key);
        if (prev == EMPTY_KEY) { inserted = true; break; }
        if (prev == key)       { inserted = false; break; }
        h = (h + 1) & (HASH_SIZE - 1);
    }
    if (!inserted) return;
    const float* xs = x + (size_t)s * D;
    const float* xd = x + (size_t)d * D;
    if (s == d) {
        float* mrow = msg + (size_t)s * D;
#pragma unroll
        for (int i = 0; i < D; ++i) atomicAdd(&mrow[i], xs[i]);
    } else {
        float* ms = msg + (size_t)s * D;
        float* md = msg + (size_t)d * D;
#pragma unroll
        for (int i = 0; i < D; ++i) {
            atomicAdd(&ms[i], xd[i]);
            atomicAdd(&md[i], xs[i]);
        }
    }
}

__global__ __launch_bounds__(256) void gnn_update(
        const float* __restrict__ x,
        float* __restrict__ out,
        const float* __restrict__ W_agg,
        const float* __restrict__ b_agg,
        const float* __restrict__ W_upd,
        const float* __restrict__ b_upd) {
    __shared__ float sWa[D][D + 1];
    __shared__ float sWu[D][D + 1];
    __shared__ float sb[D];
    __shared__ float sx[8][D];
    __shared__ float sm[8][D];
    int t = threadIdx.x;
    for (int i = t; i < D * D; i += 256) {
        sWa[i >> 5][i & 31] = W_agg[i];
        sWu[i >> 5][i & 31] = W_upd[i];
    }
    if (t < D) sb[t] = b_agg[t] + b_upd[t];
    int g = t >> 5, o = t & 31;
    size_t node = (size_t)blockIdx.x * 8 + g;
    sx[g][o] = x[node * D + o];
    sm[g][o] = out[node * D + o];
    __syncthreads();
    float acc = sb[o];
#pragma unroll
    for (int k = 0; k < D; ++k) {
        acc += sx[g][k] * sWu[o][k];
        acc += sm[g][k] * sWa[o][k];
    }
    out[node * D + o] = acc;
}

// ===========================================================================

extern "C" void kernel_launch(void* const* d_in, const int* in_sizes, int n_in,
                              void* d_out, int out_size, void* d_ws, size_t ws_size,
                              hipStream_t stream) {
    const float* x      = (const float*)d_in[0];
    const int*   eidx   = (const int*)d_in[1];
    const float* W_agg  = (const float*)d_in[2];
    const float* b_agg  = (const float*)d_in[3];
    const float* W_upd  = (const float*)d_in[4];
    const float* b_upd  = (const float*)d_in[5];
    float* out = (float*)d_out;

    const int E = in_sizes[1] / 2;
    const int N = in_sizes[0] / D;
    const int* src = eidx;
    const int* dst = eidx + E;

    const int wpr = N >> 5;                                 // words per bitmap row
    const size_t bm_bytes = (size_t)N * wpr * sizeof(unsigned int);  // 32 MiB

    if (ws_size >= bm_bytes) {
        unsigned int* bm = (unsigned int*)d_ws;
        hipMemsetAsync(bm, 0, bm_bytes, stream);
        gnn_edge_bits<<<(E + 255) / 256, 256, 0, stream>>>(src, dst, bm, E, wpr);
        gnn_gather_update<<<N / 4, 256, 0, stream>>>(bm, x, out, W_agg, b_agg,
                                                     W_upd, b_upd, wpr);
    } else {
        unsigned int* htab = (unsigned int*)d_ws;
        hipMemsetAsync(out, 0, (size_t)N * D * sizeof(float), stream);
        hipMemsetAsync(htab, 0xFF, (size_t)HASH_SIZE * sizeof(unsigned int), stream);
        gnn_edge_scatter<<<(E + 255) / 256, 256, 0, stream>>>(src, dst, x, out, htab, E);
        gnn_update<<<N / 8, 256, 0, stream>>>(x, out, W_agg, b_agg, W_upd, b_upd);
    }
}

// Round 4
// 134.912 us; speedup vs baseline: 13.3901x; 1.2698x over previous
//
#include <hip/hip_runtime.h>

#define D 32
#define CAP 384

// ===========================================================================
// FAST PATH: adjacency bitmap (atomicOr, idempotent dedup) + atomic-free
// gather with parallel bit-extraction and ILP-batched neighbor loads.
// ===========================================================================

__global__ void gnn_edge_bits(const int* __restrict__ src,
                              const int* __restrict__ dst,
                              unsigned int* __restrict__ bm,
                              int E, int wpr) {
    int e = blockIdx.x * blockDim.x + threadIdx.x;
    if (e >= E) return;
    int s = src[e];
    int d = dst[e];
    atomicOr(&bm[(size_t)d * wpr + (s >> 5)], 1u << (s & 31));
    atomicOr(&bm[(size_t)s * wpr + (d >> 5)], 1u << (d & 31));
}

__global__ __launch_bounds__(256) void gnn_gather_update(
        const unsigned int* __restrict__ bm,
        const float* __restrict__ x,
        float* __restrict__ out,
        const float* __restrict__ W_agg,
        const float* __restrict__ b_agg,
        const float* __restrict__ W_upd,
        const float* __restrict__ b_upd,
        int wpr) {
    __shared__ float sWa[D][D + 1];
    __shared__ float sWu[D][D + 1];
    __shared__ float sb[D];
    __shared__ float sx[4][D];
    __shared__ float sm[4][D];
    __shared__ int   slist[4][CAP];

    int t = threadIdx.x;
    for (int i = t; i < D * D; i += 256) {
        sWa[i >> 5][i & 31] = W_agg[i];
        sWu[i >> 5][i & 31] = W_upd[i];
    }
    if (t < D) sb[t] = b_agg[t] + b_upd[t];

    int lane = t & 63;
    int wv   = t >> 6;                    // wave slot = node slot
    int dim  = lane & 31;
    int half = lane >> 5;
    size_t node = (size_t)blockIdx.x * 4 + wv;

    if (lane < D) sx[wv][lane] = x[node * D + lane];

    // ---- load bitmap row: 8 coalesced chunks, one word per lane ----
    const unsigned int* row = bm + node * (size_t)wpr;
    unsigned int wb[8];
#pragma unroll
    for (int c = 0; c < 8; ++c) wb[c] = row[c * 64 + lane];

    // ---- parallel extraction: popcount + wave prefix -> LDS index list ----
    int myc = 0;
#pragma unroll
    for (int c = 0; c < 8; ++c) myc += __popc(wb[c]);

    int pre = myc;
#pragma unroll
    for (int off = 1; off < 64; off <<= 1) {
        int v = __shfl_up(pre, off, 64);
        if (lane >= off) pre += v;
    }
    int total = __shfl(pre, 63, 64);
    pre -= myc;                           // exclusive prefix

    if (total <= CAP) {
        int p = pre;
#pragma unroll
        for (int c = 0; c < 8; ++c) {
            unsigned int ww = wb[c];
            int base = (c * 64 + lane) * 32;
            while (ww) {
                int b = __ffs(ww) - 1;
                ww &= ww - 1;
                slist[wv][p++] = base + b;
            }
        }
    }
    __syncthreads();

    // ---- gather: halves split neighbor list, 4 independent loads/iter ----
    float acc = 0.f;
    if (total <= CAP) {
        int j = half;
        for (; j + 8 <= total; j += 8) {
            int c0 = slist[wv][j + 0];
            int c1 = slist[wv][j + 2];
            int c2 = slist[wv][j + 4];
            int c3 = slist[wv][j + 6];
            float v0 = x[(size_t)c0 * D + dim];
            float v1 = x[(size_t)c1 * D + dim];
            float v2 = x[(size_t)c2 * D + dim];
            float v3 = x[(size_t)c3 * D + dim];
            acc += v0; acc += v1; acc += v2; acc += v3;
        }
        for (; j < total; j += 2)
            acc += x[(size_t)slist[wv][j] * D + dim];
        acc += __shfl_xor(acc, 32, 64);   // combine the two halves
    } else {
        // fallback: serial ballot scan — correct for any degree
        for (int c = 0; c < 8; ++c) {
            unsigned long long m = __ballot(wb[c] != 0);
            while (m) {
                int l = __ffsll(m) - 1;
                m &= m - 1;
                unsigned int ww = __shfl(wb[c], l, 64);
                int basecol = (c * 64 + l) * 32;
                while (ww) {
                    int b = __ffs(ww) - 1;
                    ww &= ww - 1;
                    acc += x[(size_t)(basecol + b) * D + dim];
                }
            }
        }
    }
    if (lane < D) sm[wv][lane] = acc;
    __syncthreads();

    // ---- fused epilogue: out = b + x*W_upd^T + msg*W_agg^T ----
    if (t < 128) {
        int ns = t >> 5;
        int o  = t & 31;
        float r = sb[o];
#pragma unroll
        for (int k = 0; k < D; ++k)
            r += sx[ns][k] * sWu[o][k] + sm[ns][k] * sWa[o][k];
        out[((size_t)blockIdx.x * 4 + ns) * D + o] = r;
    }
}

// ===========================================================================
// FALLBACK PATH (small ws): hash-dedup + scattered atomics (round-1 code).
// ===========================================================================
#define HASH_BITS 20
#define HASH_SIZE (1u << HASH_BITS)
#define EMPTY_KEY 0xFFFFFFFFu

__global__ void gnn_edge_scatter(const int* __restrict__ src,
                                 const int* __restrict__ dst,
                                 const float* __restrict__ x,
                                 float* __restrict__ msg,
                                 unsigned int* __restrict__ htab,
                                 int E) {
    int e = blockIdx.x * blockDim.x + threadIdx.x;
    if (e >= E) return;
    int s = src[e];
    int d = dst[e];
    int a = s < d ? s : d;
    int b = s < d ? d : s;
    unsigned int key = ((unsigned int)a << 14) | (unsigned int)b;
    unsigned int h = (key * 2654435761u) >> (32 - HASH_BITS);
    bool inserted;
    for (;;) {
        unsigned int prev = atomicCAS(&htab[h], EMPTY_KEY, key);
        if (prev == EMPTY_KEY) { inserted = true; break; }
        if (prev == key)       { inserted = false; break; }
        h = (h + 1) & (HASH_SIZE - 1);
    }
    if (!inserted) return;
    const float* xs = x + (size_t)s * D;
    const float* xd = x + (size_t)d * D;
    if (s == d) {
        float* mrow = msg + (size_t)s * D;
#pragma unroll
        for (int i = 0; i < D; ++i) atomicAdd(&mrow[i], xs[i]);
    } else {
        float* ms = msg + (size_t)s * D;
        float* md = msg + (size_t)d * D;
#pragma unroll
        for (int i = 0; i < D; ++i) {
            atomicAdd(&ms[i], xd[i]);
            atomicAdd(&md[i], xs[i]);
        }
    }
}

__global__ __launch_bounds__(256) void gnn_update(
        const float* __restrict__ x,
        float* __restrict__ out,
        const float* __restrict__ W_agg,
        const float* __restrict__ b_agg,
        const float* __restrict__ W_upd,
        const float* __restrict__ b_upd) {
    __shared__ float sWa[D][D + 1];
    __shared__ float sWu[D][D + 1];
    __shared__ float sb[D];
    __shared__ float sx[8][D];
    __shared__ float sm[8][D];
    int t = threadIdx.x;
    for (int i = t; i < D * D; i += 256) {
        sWa[i >> 5][i & 31] = W_agg[i];
        sWu[i >> 5][i & 31] = W_upd[i];
    }
    if (t < D) sb[t] = b_agg[t] + b_upd[t];
    int g = t >> 5, o = t & 31;
    size_t node = (size_t)blockIdx.x * 8 + g;
    sx[g][o] = x[node * D + o];
    sm[g][o] = out[node * D + o];
    __syncthreads();
    float acc = sb[o];
#pragma unroll
    for (int k = 0; k < D; ++k) {
        acc += sx[g][k] * sWu[o][k];
        acc += sm[g][k] * sWa[o][k];
    }
    out[node * D + o] = acc;
}

// ===========================================================================

extern "C" void kernel_launch(void* const* d_in, const int* in_sizes, int n_in,
                              void* d_out, int out_size, void* d_ws, size_t ws_size,
                              hipStream_t stream) {
    const float* x      = (const float*)d_in[0];
    const int*   eidx   = (const int*)d_in[1];
    const float* W_agg  = (const float*)d_in[2];
    const float* b_agg  = (const float*)d_in[3];
    const float* W_upd  = (const float*)d_in[4];
    const float* b_upd  = (const float*)d_in[5];
    float* out = (float*)d_out;

    const int E = in_sizes[1] / 2;
    const int N = in_sizes[0] / D;
    const int* src = eidx;
    const int* dst = eidx + E;

    const int wpr = N >> 5;
    const size_t bm_bytes = (size_t)N * wpr * sizeof(unsigned int);  // 32 MiB

    if (ws_size >= bm_bytes) {
        unsigned int* bm = (unsigned int*)d_ws;
        hipMemsetAsync(bm, 0, bm_bytes, stream);
        gnn_edge_bits<<<(E + 255) / 256, 256, 0, stream>>>(src, dst, bm, E, wpr);
        gnn_gather_update<<<N / 4, 256, 0, stream>>>(bm, x, out, W_agg, b_agg,
                                                     W_upd, b_upd, wpr);
    } else {
        unsigned int* htab = (unsigned int*)d_ws;
        hipMemsetAsync(out, 0, (size_t)N * D * sizeof(float), stream);
        hipMemsetAsync(htab, 0xFF, (size_t)HASH_SIZE * sizeof(unsigned int), stream);
        gnn_edge_scatter<<<(E + 255) / 256, 256, 0, stream>>>(src, dst, x, out, htab, E);
        gnn_update<<<N / 8, 256, 0, stream>>>(x, out, W_agg, b_agg, W_upd, b_upd);
    }
}